// Round 1
// baseline (357.783 us; speedup 1.0000x reference)
//
#include <hip/hip_runtime.h>
#include <math.h>

// ---------------------------------------------------------------------------
// TemporalSSMPatchwise: b=8,t=15,H=480,W=640, PS=8 -> hp=60,wp=80,n=4800
// d=64, P=32, pp=64.  N_seq = 8*4800 = 38400.
// Only the last timestep feeds the head => fuse embed+LN+Bu+scan (K1),
// then LN3 + W_out GEMM + pixel-shuffle scatter (K2).  K0 pre-packs all
// weight matrices into bf16 MFMA B-operand "register images" in d_ws.
// MFMA 16x16x32 bf16: A[m=lane&15][k=(lane>>4)*8+j], B[k][n=lane&15],
// C/D: col=lane&15, row=(lane>>4)*4+reg  (m89/m91-verified layouts).
// ---------------------------------------------------------------------------

typedef __attribute__((ext_vector_type(8))) short short8;
typedef __attribute__((ext_vector_type(4))) short short4v;
typedef __attribute__((ext_vector_type(4))) float f32x4;

#define MFMA16(a, b, c) __builtin_amdgcn_mfma_f32_16x16x32_bf16((a), (b), (c), 0, 0, 0)

__device__ __forceinline__ short f2bf(float f) {
  union { float f; unsigned u; } v; v.f = f;
  unsigned r = (v.u + 0x7fffu + ((v.u >> 16) & 1u)) >> 16;  // RNE
  return (short)r;
}
__device__ __forceinline__ float geluf(float x) {
  return 0.5f * x * (1.0f + erff(x * 0.70710678118654752f));
}
__device__ __forceinline__ float sum4(float4 v) { return v.x + v.y + v.z + v.w; }
__device__ __forceinline__ float dot4(float4 v) { return v.x*v.x + v.y*v.y + v.z*v.z + v.w*v.w; }

// (Lbar-1)/Lam factors for state-input matrix Bbar
__device__ __forceinline__ void bbar_factors(const float* Lre, const float* Lim,
                                             const float* lstep, int p,
                                             float& fre, float& fim) {
  float st = expf(lstep[p]);
  float lr = Lre[p], li = Lim[p];
  float er = expf(lr * st);
  float lbr = er * cosf(li * st), lbi = er * sinf(li * st);
  float u = lbr - 1.0f, v = lbi;
  float den = lr * lr + li * li;
  fre = (u * lr + v * li) / den;
  fim = (v * lr - u * li) / den;
}

// ---------------------------------------------------------------------------
// K0: pack 176 B-operand fragments (bf16 register images, 1KB each) + bu0.
// frag ids: 0..7 W_embed | 8..15 Bbar' (g1-folded) | 16..23 Cc2 (mask-folded)
//           24..39 W_enc | 40..47 W_dec | 48..175 W_out
// ---------------------------------------------------------------------------
__global__ __launch_bounds__(256) void k0_prep(
    const float* __restrict__ W_embed, const float* __restrict__ g1,
    const float* __restrict__ be1, const float* __restrict__ Lre,
    const float* __restrict__ Lim, const float* __restrict__ Bre,
    const float* __restrict__ Bim, const float* __restrict__ Cre,
    const float* __restrict__ Cim, const float* __restrict__ lstep,
    const float* __restrict__ W_enc, const float* __restrict__ W_dec,
    const float* __restrict__ W_out, short* __restrict__ wimg,
    float* __restrict__ bu0) {
  const int bid = blockIdx.x;
  if (bid == 44) {  // bu0[q] = sum_d beta1[d] * Bbar_comp[p,d]  (no g1 fold)
    int q = threadIdx.x;
    if (q < 64) {
      int c = q >> 5, p = q & 31;
      float fre, fim; bbar_factors(Lre, Lim, lstep, p, fre, fim);
      float s = 0.f;
      for (int d = 0; d < 64; ++d) {
        float br = Bre[p * 64 + d], bi = Bim[p * 64 + d];
        float val = c ? (fre * bi + fim * br) : (fre * br - fim * bi);
        s += be1[d] * val;
      }
      bu0[q] = s;
    }
    return;
  }
  const int w = threadIdx.x >> 6, lane = threadIdx.x & 63;
  const int l15 = lane & 15, qd = lane >> 4;
  const int f = bid * 4 + w;
  short v[8];
  if (f < 8) {
    int nt = f >> 1, kt = f & 1, n = nt * 16 + l15, k0 = kt * 32 + qd * 8;
#pragma unroll
    for (int j = 0; j < 8; ++j) v[j] = f2bf(W_embed[n * 64 + k0 + j]);
  } else if (f < 16) {
    int fi = f - 8, nt = fi >> 1, kt = fi & 1;
    int rq = nt * 16 + l15, c = rq >> 5, p = rq & 31, d0 = kt * 32 + qd * 8;
    float fre, fim; bbar_factors(Lre, Lim, lstep, p, fre, fim);
#pragma unroll
    for (int j = 0; j < 8; ++j) {
      int d = d0 + j;
      float br = Bre[p * 64 + d], bi = Bim[p * 64 + d];
      float val = c ? (fre * bi + fim * br) : (fre * br - fim * bi);
      v[j] = f2bf(g1[d] * val);
    }
  } else if (f < 24) {
    int fi = f - 16, nt = fi >> 1, kt = fi & 1;
    int d = nt * 16 + l15, q0 = kt * 32 + qd * 8;
#pragma unroll
    for (int j = 0; j < 8; ++j) {
      int qq = q0 + j, p = qq & 31;
      float stp = expf(lstep[p]);
      float fr = stp * fabsf(Lim[p]) * (1.0f / 6.28318530717958648f);
      float m = (fr < 0.5f) ? 1.f : 0.f;
      float val = (qq < 32) ? Cre[d * 32 + p] * m : -Cim[d * 32 + p] * m;
      v[j] = f2bf(val);
    }
  } else if (f < 40) {
    int fi = f - 24, nt = fi >> 1, kt = fi & 1, row = nt * 16 + l15;
#pragma unroll
    for (int j = 0; j < 8; ++j) v[j] = f2bf(W_enc[row * 64 + kt * 32 + qd * 8 + j]);
  } else if (f < 48) {
    int fi = f - 40, kt = fi & 1, row = (fi >> 1) * 16 + l15;
#pragma unroll
    for (int j = 0; j < 8; ++j) v[j] = f2bf(W_dec[row * 64 + kt * 32 + qd * 8 + j]);
  } else {
    int fi = f - 48, nt = fi >> 1, kt = fi & 1, row = nt * 16 + l15;
#pragma unroll
    for (int j = 0; j < 8; ++j) v[j] = f2bf(W_out[row * 64 + kt * 32 + qd * 8 + j]);
  }
  short8 sv;
#pragma unroll
  for (int j = 0; j < 8; ++j) sv[j] = v[j];
  *(short8*)&wimg[(f * 64 + lane) * 8] = sv;
}

// LN stats over d=64 for 4 sequences (one per C-reg) in C-layout.
__device__ __forceinline__ void ln_stats(const f32x4* tl, f32x4& mean, f32x4& rstd) {
  f32x4 s = tl[0] + tl[1] + tl[2] + tl[3];
  f32x4 s2 = tl[0] * tl[0] + tl[1] * tl[1] + tl[2] * tl[2] + tl[3] * tl[3];
#pragma unroll
  for (int m = 1; m < 16; m <<= 1) {
#pragma unroll
    for (int i = 0; i < 4; ++i) {
      s[i] += __shfl_xor(s[i], m);
      s2[i] += __shfl_xor(s2[i], m);
    }
  }
  mean = s * 0.015625f;
  f32x4 var = s2 * 0.015625f - mean * mean;
#pragma unroll
  for (int i = 0; i < 4; ++i) rstd[i] = rsqrtf(var[i] + 1e-5f);
}

// C-layout (4 f32x4 tiles) -> bf16 A-operand fragments, via padded LDS stage.
__device__ __forceinline__ void stage_CtoA(short* st, const f32x4* tiles,
                                           int qd, int l15, short8* out) {
#pragma unroll
  for (int nt = 0; nt < 4; ++nt)
#pragma unroll
    for (int r = 0; r < 4; ++r)
      st[(qd * 4 + r) * 68 + nt * 16 + l15] = f2bf(tiles[nt][r]);
  __asm__ volatile("s_waitcnt lgkmcnt(0)" ::: "memory");
#pragma unroll
  for (int kt = 0; kt < 2; ++kt) {
    const short* sp = st + l15 * 68 + kt * 32 + qd * 8;
    short4v lo = *(const short4v*)sp;
    short4v hi = *(const short4v*)(sp + 4);
    short8 o;
    o[0] = lo[0]; o[1] = lo[1]; o[2] = lo[2]; o[3] = lo[3];
    o[4] = hi[0]; o[5] = hi[1]; o[6] = hi[2]; o[7] = hi[3];
    out[kt] = o;
  }
  __asm__ volatile("s_waitcnt lgkmcnt(0)" ::: "memory");
}

// ---------------------------------------------------------------------------
// K1: fused embed -> LN1 -> Bu -> 15-step scan -> head (through MLP) -> xlast
// 128 threads = 2 waves, 16 seqs/wave, grid 1200.
// ---------------------------------------------------------------------------
__global__ __launch_bounds__(128) void k1_fused(
    const float* __restrict__ x, const short* __restrict__ wimg_g,
    const float* __restrict__ bu0_g, const float* __restrict__ Lre,
    const float* __restrict__ Lim, const float* __restrict__ lstep,
    const float* __restrict__ g1, const float* __restrict__ be1,
    const float* __restrict__ bemb, const float* __restrict__ Dv,
    const float* __restrict__ g2, const float* __restrict__ be2,
    float* __restrict__ xlast) {
  __shared__ short wimg[48 * 512];      // 48 KB weight frag images
  __shared__ short stage[2][16 * 68];   // per-wave staging, stride-68 pad
  {
    float4* dst = (float4*)wimg;
    const float4* src = (const float4*)wimg_g;
    for (int i = threadIdx.x; i < 3072; i += 128) dst[i] = src[i];
  }
  __syncthreads();

  const int wv = threadIdx.x >> 6;
  const int lane = threadIdx.x & 63;
  const int l15 = lane & 15, qd = lane >> 4;
  short* st = &stage[wv][0];

  const int sbase = (blockIdx.x * 2 + wv) * 16;  // 16 consecutive seqs
  const int b_i = sbase / 4800;
  const int pr = sbase % 4800;
  const int ph = pr / 80;
  const int pw0 = pr % 80;  // multiple of 16, so +l15 stays in-row

  const float* xbase = x + ((b_i * 15) * 480 + ph * 8) * 640 + (pw0 + l15) * 8;

  float g1c[4], b1c[4], bec[4], Dc[4], g2c[4], b2c[4], bu0c[4];
#pragma unroll
  for (int nt = 0; nt < 4; ++nt) {
    int col = nt * 16 + l15;
    g1c[nt] = g1[col]; b1c[nt] = be1[col]; bec[nt] = bemb[col];
    Dc[nt] = Dv[col];  g2c[nt] = g2[col];  b2c[nt] = be2[col];
    bu0c[nt] = bu0_g[col];
  }
  // Lbar for p = l15 (tiles 0/2) and p = l15+16 (tiles 1/3)
  float st0 = expf(lstep[l15]), st1 = expf(lstep[l15 + 16]);
  float er0 = expf(Lre[l15] * st0), er1 = expf(Lre[l15 + 16] * st1);
  float lbr0 = er0 * cosf(Lim[l15] * st0), lbi0 = er0 * sinf(Lim[l15] * st0);
  float lbr1 = er1 * cosf(Lim[l15 + 16] * st1), lbi1 = er1 * sinf(Lim[l15 + 16] * st1);

  const f32x4 zf = {0.f, 0.f, 0.f, 0.f};
  f32x4 state[4] = {zf, zf, zf, zf};  // C-layout: re tiles 0,1 / im tiles 2,3
  f32x4 xh[4];                        // last xhat (C-layout)

  for (int t = 0; t < 15; ++t) {
    const float* xt = xbase + t * 307200;
    short8 pa[2];
#pragma unroll
    for (int kt = 0; kt < 2; ++kt) {
      const float* rp = xt + (kt * 4 + qd) * 640;
      float4 v0 = *(const float4*)rp;
      float4 v1 = *(const float4*)(rp + 4);
      short8 p8;
      p8[0] = f2bf(v0.x); p8[1] = f2bf(v0.y); p8[2] = f2bf(v0.z); p8[3] = f2bf(v0.w);
      p8[4] = f2bf(v1.x); p8[5] = f2bf(v1.y); p8[6] = f2bf(v1.z); p8[7] = f2bf(v1.w);
      pa[kt] = p8;
    }
    f32x4 c1[4];
#pragma unroll
    for (int nt = 0; nt < 4; ++nt) {
      f32x4 acc = zf;
      acc = MFMA16(pa[0], *(const short8*)&wimg[(nt * 2 + 0) * 512 + lane * 8], acc);
      acc = MFMA16(pa[1], *(const short8*)&wimg[(nt * 2 + 1) * 512 + lane * 8], acc);
      c1[nt] = acc + bec[nt];
    }
    f32x4 mean, rstd;
    ln_stats(c1, mean, rstd);
#pragma unroll
    for (int nt = 0; nt < 4; ++nt) xh[nt] = (c1[nt] - mean) * rstd;
    short8 xa[2];
    stage_CtoA(st, xh, qd, l15, xa);
    // state = Lbar*state + bu0, then += xhat @ Bbar'^T via MFMA
    f32x4 t0 = state[0], t1 = state[1], t2 = state[2], t3 = state[3];
    state[0] = lbr0 * t0 - lbi0 * t2 + bu0c[0];
    state[1] = lbr1 * t1 - lbi1 * t3 + bu0c[1];
    state[2] = lbr0 * t2 + lbi0 * t0 + bu0c[2];
    state[3] = lbr1 * t3 + lbi1 * t1 + bu0c[3];
#pragma unroll
    for (int nt = 0; nt < 4; ++nt) {
      state[nt] = MFMA16(xa[0], *(const short8*)&wimg[(8 + nt * 2 + 0) * 512 + lane * 8], state[nt]);
      state[nt] = MFMA16(xa[1], *(const short8*)&wimg[(8 + nt * 2 + 1) * 512 + lane * 8], state[nt]);
    }
  }

  // ---- head at t = 14 ----
  f32x4 fxl[4];
#pragma unroll
  for (int nt = 0; nt < 4; ++nt) fxl[nt] = xh[nt] * g1c[nt] + b1c[nt];

  short8 xsa[2];
  stage_CtoA(st, state, qd, l15, xsa);
  f32x4 ys[4];
#pragma unroll
  for (int nt = 0; nt < 4; ++nt) {
    f32x4 acc = fxl[nt] * Dc[nt];
    acc = MFMA16(xsa[0], *(const short8*)&wimg[(16 + nt * 2 + 0) * 512 + lane * 8], acc);
    acc = MFMA16(xsa[1], *(const short8*)&wimg[(16 + nt * 2 + 1) * 512 + lane * 8], acc);
    ys[nt] = acc;
  }
  f32x4 xbv[4];
#pragma unroll
  for (int nt = 0; nt < 4; ++nt)
#pragma unroll
    for (int i = 0; i < 4; ++i) xbv[nt][i] = geluf(ys[nt][i]) + fxl[nt][i];

  f32x4 mean2, rstd2;
  ln_stats(xbv, mean2, rstd2);
  f32x4 fx2[4];
#pragma unroll
  for (int nt = 0; nt < 4; ++nt)
    fx2[nt] = (xbv[nt] - mean2) * rstd2 * g2c[nt] + b2c[nt];

  short8 fa[2];
  stage_CtoA(st, fx2, qd, l15, fa);
  f32x4 e[8];
#pragma unroll
  for (int m = 0; m < 8; ++m) {
    f32x4 acc = zf;
    acc = MFMA16(fa[0], *(const short8*)&wimg[(24 + m * 2 + 0) * 512 + lane * 8], acc);
    acc = MFMA16(fa[1], *(const short8*)&wimg[(24 + m * 2 + 1) * 512 + lane * 8], acc);
    e[m] = acc;
  }
  f32x4 hv[4];
#pragma unroll
  for (int nt = 0; nt < 4; ++nt)
#pragma unroll
    for (int i = 0; i < 4; ++i) hv[nt][i] = e[nt][i] * geluf(e[nt + 4][i]);

  short8 ha[2];
  stage_CtoA(st, hv, qd, l15, ha);
#pragma unroll
  for (int nt = 0; nt < 4; ++nt) {
    f32x4 acc = fx2[nt];  // residual
    acc = MFMA16(ha[0], *(const short8*)&wimg[(40 + nt * 2 + 0) * 512 + lane * 8], acc);
    acc = MFMA16(ha[1], *(const short8*)&wimg[(40 + nt * 2 + 1) * 512 + lane * 8], acc);
#pragma unroll
    for (int r = 0; r < 4; ++r)
      xlast[(sbase + qd * 4 + r) * 64 + nt * 16 + l15] = acc[r];
  }
}

// ---------------------------------------------------------------------------
// K2: LN3 + x_last @ W_out^T + b_out -> pixel-shuffle scatter into y.
// 256 threads = 4 waves; block = 64 seqs x 256 out-cols; grid 600*4 = 2400.
// ---------------------------------------------------------------------------
__global__ __launch_bounds__(256) void k2_head(
    const float* __restrict__ xlast, const short* __restrict__ wout_img,
    const float* __restrict__ g3, const float* __restrict__ be3,
    const float* __restrict__ b_out, float* __restrict__ y) {
  __shared__ short wo[32 * 512];  // 32 KB: one N-quarter of W_out frags
  const int nqb = blockIdx.x & 3;
  const int mblk = blockIdx.x >> 2;
  {
    float4* dst = (float4*)wo;
    const float4* src = (const float4*)(wout_img + nqb * 32 * 512);
    for (int i = threadIdx.x; i < 2048; i += 256) dst[i] = src[i];
  }
  __syncthreads();
  const int wv = threadIdx.x >> 6, lane = threadIdx.x & 63;
  const int l15 = lane & 15, qd = lane >> 4;
  const int sbase = mblk * 64 + wv * 16;
  const int nq0 = nqb * 256;
  const int seq = sbase + l15;
  const float* xr = xlast + seq * 64;
  float4 a0 = *(const float4*)(xr + qd * 8);
  float4 a1 = *(const float4*)(xr + qd * 8 + 4);
  float4 a2 = *(const float4*)(xr + 32 + qd * 8);
  float4 a3 = *(const float4*)(xr + 32 + qd * 8 + 4);
  float sum = sum4(a0) + sum4(a1) + sum4(a2) + sum4(a3);
  float ssq = dot4(a0) + dot4(a1) + dot4(a2) + dot4(a3);
  sum += __shfl_xor(sum, 16); sum += __shfl_xor(sum, 32);
  ssq += __shfl_xor(ssq, 16); ssq += __shfl_xor(ssq, 32);
  float mean = sum * (1.f / 64.f);
  float rstd = rsqrtf(ssq * (1.f / 64.f) - mean * mean + 1e-5f);
  float4 ga = *(const float4*)(g3 + qd * 8);
  float4 gb = *(const float4*)(g3 + qd * 8 + 4);
  float4 gc = *(const float4*)(g3 + 32 + qd * 8);
  float4 gd2 = *(const float4*)(g3 + 32 + qd * 8 + 4);
  float4 ba = *(const float4*)(be3 + qd * 8);
  float4 bb = *(const float4*)(be3 + qd * 8 + 4);
  float4 bc = *(const float4*)(be3 + 32 + qd * 8);
  float4 bd = *(const float4*)(be3 + 32 + qd * 8 + 4);
#define ZC(av, gv, bv) f2bf(((av)-mean) * rstd * (gv) + (bv))
  short8 za0, za1;
  za0[0] = ZC(a0.x, ga.x, ba.x); za0[1] = ZC(a0.y, ga.y, ba.y);
  za0[2] = ZC(a0.z, ga.z, ba.z); za0[3] = ZC(a0.w, ga.w, ba.w);
  za0[4] = ZC(a1.x, gb.x, bb.x); za0[5] = ZC(a1.y, gb.y, bb.y);
  za0[6] = ZC(a1.z, gb.z, bb.z); za0[7] = ZC(a1.w, gb.w, bb.w);
  za1[0] = ZC(a2.x, gc.x, bc.x); za1[1] = ZC(a2.y, gc.y, bc.y);
  za1[2] = ZC(a2.z, gc.z, bc.z); za1[3] = ZC(a2.w, gc.w, bc.w);
  za1[4] = ZC(a3.x, gd2.x, bd.x); za1[5] = ZC(a3.y, gd2.y, bd.y);
  za1[6] = ZC(a3.z, gd2.z, bd.z); za1[7] = ZC(a3.w, gd2.w, bd.w);
#undef ZC
  int ob[4];
#pragma unroll
  for (int r = 0; r < 4; ++r) {
    int sr = sbase + qd * 4 + r;
    int bi = sr / 4800, prr = sr % 4800;
    int phh = prr / 80, pww = prr % 80;
    ob[r] = (bi * 16 * 480 + phh * 8) * 640 + pww * 8;
  }
#pragma unroll
  for (int nt = 0; nt < 16; ++nt) {
    int o = nq0 + nt * 16 + l15;
    float bo = b_out[o];
    f32x4 acc = {bo, bo, bo, bo};
    acc = MFMA16(za0, *(const short8*)&wo[(nt * 2 + 0) * 512 + lane * 8], acc);
    acc = MFMA16(za1, *(const short8*)&wo[(nt * 2 + 1) * 512 + lane * 8], acc);
    int c = o >> 6, pi = (o >> 3) & 7, pj = o & 7;
    int off = c * 307200 + pi * 640 + pj;
#pragma unroll
    for (int r = 0; r < 4; ++r) y[ob[r] + off] = acc[r];
  }
}

// ---------------------------------------------------------------------------
extern "C" void kernel_launch(void* const* d_in, const int* in_sizes, int n_in,
                              void* d_out, int out_size, void* d_ws, size_t ws_size,
                              hipStream_t stream) {
  const float* x       = (const float*)d_in[0];
  const float* W_embed = (const float*)d_in[1];
  const float* b_embed = (const float*)d_in[2];
  const float* g1      = (const float*)d_in[3];
  const float* beta1   = (const float*)d_in[4];
  const float* Lre     = (const float*)d_in[5];
  const float* Lim     = (const float*)d_in[6];
  const float* Bre     = (const float*)d_in[7];
  const float* Bim     = (const float*)d_in[8];
  const float* Cre     = (const float*)d_in[9];
  const float* Cim     = (const float*)d_in[10];
  const float* Dv      = (const float*)d_in[11];
  const float* lstep   = (const float*)d_in[12];
  const float* g2      = (const float*)d_in[13];
  const float* beta2   = (const float*)d_in[14];
  const float* W_enc   = (const float*)d_in[15];
  const float* W_dec   = (const float*)d_in[16];
  const float* g3      = (const float*)d_in[17];
  const float* beta3   = (const float*)d_in[18];
  const float* W_out   = (const float*)d_in[19];
  const float* b_out   = (const float*)d_in[20];
  float* y = (float*)d_out;

  short* wimg = (short*)d_ws;                              // 176 KB frag images
  float* bu0  = (float*)((char*)d_ws + 176 * 1024);        // 256 B
  float* xlast = (float*)((char*)d_ws + 180 * 1024);       // 38400*64*4 = 9.83 MB

  k0_prep<<<dim3(45), dim3(256), 0, stream>>>(W_embed, g1, beta1, Lre, Lim,
                                              Bre, Bim, Cre, Cim, lstep,
                                              W_enc, W_dec, W_out, wimg, bu0);
  k1_fused<<<dim3(1200), dim3(128), 0, stream>>>(x, wimg, bu0, Lre, Lim, lstep,
                                                 g1, beta1, b_embed, Dv, g2,
                                                 beta2, xlast);
  k2_head<<<dim3(2400), dim3(256), 0, stream>>>(xlast, wimg + 48 * 512, g3,
                                                beta3, b_out, y);
}

// Round 2
// 352.230 us; speedup vs baseline: 1.0158x; 1.0158x over previous
//
#include <hip/hip_runtime.h>
#include <math.h>

// ---------------------------------------------------------------------------
// TemporalSSMPatchwise: b=8,t=15,H=480,W=640, PS=8 -> hp=60,wp=80, n=4800
// d=64, P=32, pp=64.  N_seq = 38400.
// Transpose-free dataflow: weights are MFMA A-operands (pre-permuted rows),
// activations are B-operands.  With row-perm chan(nt,qd,r) =
// (nt>>1)*32 + qd*8 + (nt&1)*4 + r, the D-output register layout of one
// matmul IS the B-operand layout of the next (k-slot = kt*32+qd*8+j,
// identity on channel index).  No LDS staging, LN = 2 shfl_xor.
// MFMA 16x16x32 bf16: A[m=lane&15][k=qd*8+j], B[k=qd*8+j][n=lane&15],
// D: col=lane&15, row=qd*4+reg (m89/m91-verified).
// ---------------------------------------------------------------------------

typedef __attribute__((ext_vector_type(8))) short short8;
typedef __attribute__((ext_vector_type(4))) float f32x4;

#define MFMA16(a, b, c) __builtin_amdgcn_mfma_f32_16x16x32_bf16((a), (b), (c), 0, 0, 0)

__device__ __forceinline__ short f2bf(float f) {
  union { float f; unsigned u; } v; v.f = f;
  unsigned r = (v.u + 0x7fffu + ((v.u >> 16) & 1u)) >> 16;  // RNE
  return (short)r;
}
__device__ __forceinline__ float geluf(float x) {
  return 0.5f * x * (1.0f + erff(x * 0.70710678118654752f));
}
// pack two C-layout f32x4 tiles (2kt, 2kt+1) into one bf16 B-operand frag
__device__ __forceinline__ short8 packfrag(const f32x4& a, const f32x4& b) {
  short8 o;
  o[0] = f2bf(a[0]); o[1] = f2bf(a[1]); o[2] = f2bf(a[2]); o[3] = f2bf(a[3]);
  o[4] = f2bf(b[0]); o[5] = f2bf(b[1]); o[6] = f2bf(b[2]); o[7] = f2bf(b[3]);
  return o;
}
// weight-row permutation: A-row a = i*16+m  ->  actual channel
__device__ __forceinline__ int ecmap(int i, int m) {
  return (i >> 1) * 32 + (m >> 2) * 8 + (i & 1) * 4 + (m & 3);
}
__device__ __forceinline__ void bbar_factors(const float* Lre, const float* Lim,
                                             const float* lstep, int p,
                                             float& fre, float& fim) {
  float st = expf(lstep[p]);
  float lr = Lre[p], li = Lim[p];
  float er = expf(lr * st);
  float lbr = er * cosf(li * st), lbi = er * sinf(li * st);
  float u = lbr - 1.0f, v = lbi;
  float den = lr * lr + li * li;
  fre = (u * lr + v * li) / den;
  fim = (v * lr - u * li) / den;
}

// ---------------------------------------------------------------------------
// K0: pack 176 A-operand fragments (1 KB each) + bu0.
// ids: 0..7 W_embed | 8..15 Bbar'(g1-folded) | 16..23 Cc2(mask-folded)
//      24..39 W_enc | 40..47 W_dec | 48..175 W_out (natural rows)
// frag(i,kt) value[j] at lane(qd,m): A[i*16+m][k=kt*32+qd*8+j]
// ---------------------------------------------------------------------------
__global__ __launch_bounds__(256) void k0_prep(
    const float* __restrict__ W_embed, const float* __restrict__ g1,
    const float* __restrict__ be1, const float* __restrict__ Lre,
    const float* __restrict__ Lim, const float* __restrict__ Bre,
    const float* __restrict__ Bim, const float* __restrict__ Cre,
    const float* __restrict__ Cim, const float* __restrict__ lstep,
    const float* __restrict__ W_enc, const float* __restrict__ W_dec,
    const float* __restrict__ W_out, short* __restrict__ wimg,
    float* __restrict__ bu0) {
  const int bid = blockIdx.x;
  if (bid == 44) {  // bu0[q] = sum_d beta1[d] * Bbar_comp[p][d]
    int q = threadIdx.x;
    if (q < 64) {
      int c = q >> 5, p = q & 31;
      float fre, fim; bbar_factors(Lre, Lim, lstep, p, fre, fim);
      float s = 0.f;
      for (int d = 0; d < 64; ++d) {
        float br = Bre[p * 64 + d], bi = Bim[p * 64 + d];
        float val = c ? (fre * bi + fim * br) : (fre * br - fim * bi);
        s += be1[d] * val;
      }
      bu0[q] = s;
    }
    return;
  }
  const int w = threadIdx.x >> 6, lane = threadIdx.x & 63;
  const int m = lane & 15, qd = lane >> 4;
  const int f = bid * 4 + w;
  short v[8];
  if (f < 8) {
    int i = f >> 1, kt = f & 1, chan = ecmap(i, m), k0 = kt * 32 + qd * 8;
#pragma unroll
    for (int j = 0; j < 8; ++j) v[j] = f2bf(W_embed[chan * 64 + k0 + j]);
  } else if (f < 16) {
    int fi = f - 8, i = fi >> 1, kt = fi & 1;
    int comp = i & 1, p = (i >> 1) * 16 + m, d0 = kt * 32 + qd * 8;
    float fre, fim; bbar_factors(Lre, Lim, lstep, p, fre, fim);
#pragma unroll
    for (int j = 0; j < 8; ++j) {
      int d = d0 + j;
      float br = Bre[p * 64 + d], bi = Bim[p * 64 + d];
      float val = comp ? (fre * bi + fim * br) : (fre * br - fim * bi);
      v[j] = f2bf(g1[d] * val);
    }
  } else if (f < 24) {
    int fi = f - 16, i = fi >> 1, kt = fi & 1, chan = ecmap(i, m);
#pragma unroll
    for (int j = 0; j < 8; ++j) {
      int comp = j >> 2, p = kt * 16 + qd * 4 + (j & 3);
      float stp = expf(lstep[p]);
      float fr = stp * fabsf(Lim[p]) * (1.0f / 6.28318530717958648f);
      float msk = (fr < 0.5f) ? 1.f : 0.f;
      float val = comp ? -Cim[chan * 32 + p] * msk : Cre[chan * 32 + p] * msk;
      v[j] = f2bf(val);
    }
  } else if (f < 40) {
    int fi = f - 24, i = fi >> 1, kt = fi & 1;
    int row = (i < 4) ? ecmap(i, m) : 64 + ecmap(i - 4, m);
#pragma unroll
    for (int j = 0; j < 8; ++j) v[j] = f2bf(W_enc[row * 64 + kt * 32 + qd * 8 + j]);
  } else if (f < 48) {
    int fi = f - 40, i = fi >> 1, kt = fi & 1, row = ecmap(i, m);
#pragma unroll
    for (int j = 0; j < 8; ++j) v[j] = f2bf(W_dec[row * 64 + kt * 32 + qd * 8 + j]);
  } else {
    int fi = f - 48, i = fi >> 1, kt = fi & 1, row = i * 16 + m;  // natural
#pragma unroll
    for (int j = 0; j < 8; ++j) v[j] = f2bf(W_out[row * 64 + kt * 32 + qd * 8 + j]);
  }
  short8 sv;
#pragma unroll
  for (int j = 0; j < 8; ++j) sv[j] = v[j];
  *(short8*)&wimg[(f * 64 + lane) * 8] = sv;
}

// ---------------------------------------------------------------------------
// K1: embed -> LN1 -> Bu -> scan -> head(MLP) -> xlast^T.  256 thr = 4 waves,
// 16 seqs/wave, grid 600.  LDS = 48KB weights only -> 3 blocks/CU.
// ---------------------------------------------------------------------------
__global__ __launch_bounds__(256) void k1_fused(
    const float* __restrict__ x, const short* __restrict__ wimg_g,
    const float* __restrict__ bu0_g, const float* __restrict__ Lre,
    const float* __restrict__ Lim, const float* __restrict__ lstep,
    const float* __restrict__ g1, const float* __restrict__ be1,
    const float* __restrict__ bemb, const float* __restrict__ Dv,
    const float* __restrict__ g2, const float* __restrict__ be2,
    float* __restrict__ xlastT) {
  __shared__ short wimg[48 * 512];
  {
    float4* dst = (float4*)wimg;
    const float4* src = (const float4*)wimg_g;
    for (int i = threadIdx.x; i < 3072; i += 256) dst[i] = src[i];
  }
  __syncthreads();
#define WF(id) (*(const short8*)&wimg[(id) * 512 + lane * 8])

  const int wv = threadIdx.x >> 6, lane = threadIdx.x & 63;
  const int s = lane & 15, qd = lane >> 4;
  const int sbase = (blockIdx.x * 4 + wv) * 16;
  const int b_i = sbase / 4800;
  const int pr = sbase % 4800;
  const int ph = pr / 80;
  const int pw0 = pr % 80;
  const float* xbase = x + ((b_i * 15) * 480 + ph * 8) * 640 + (pw0 + s) * 8;

  int cb[4];
  f32x4 bec[4], bu0c[4];
#pragma unroll
  for (int nt = 0; nt < 4; ++nt) {
    cb[nt] = (nt >> 1) * 32 + qd * 8 + (nt & 1) * 4;
    bec[nt] = *(const f32x4*)(bemb + cb[nt]);
    bu0c[nt] = *(const f32x4*)(bu0_g + (nt & 1) * 32 + (nt >> 1) * 16 + qd * 4);
  }
  f32x4 lbr[2], lbi[2];
#pragma unroll
  for (int k = 0; k < 2; ++k)
#pragma unroll
    for (int r = 0; r < 4; ++r) {
      int p = k * 16 + qd * 4 + r;
      float st = expf(lstep[p]);
      float er = expf(Lre[p] * st);
      lbr[k][r] = er * cosf(Lim[p] * st);
      lbi[k][r] = er * sinf(Lim[p] * st);
    }

  const f32x4 zf = {0.f, 0.f, 0.f, 0.f};
  f32x4 state[4] = {zf, zf, zf, zf};
  f32x4 xh[4];

  f32x4 vcur[4], vnext[4];
#pragma unroll
  for (int kt = 0; kt < 2; ++kt) {
    const float* rp = xbase + (kt * 4 + qd) * 640;
    vcur[kt * 2] = *(const f32x4*)rp;
    vcur[kt * 2 + 1] = *(const f32x4*)(rp + 4);
  }

  for (int t = 0; t < 15; ++t) {
    if (t < 14) {
      const float* xn = xbase + (t + 1) * 307200;
#pragma unroll
      for (int kt = 0; kt < 2; ++kt) {
        const float* rp = xn + (kt * 4 + qd) * 640;
        vnext[kt * 2] = *(const f32x4*)rp;
        vnext[kt * 2 + 1] = *(const f32x4*)(rp + 4);
      }
    }
    short8 pa0 = packfrag(vcur[0], vcur[1]);
    short8 pa1 = packfrag(vcur[2], vcur[3]);
    f32x4 c1[4];
#pragma unroll
    for (int i = 0; i < 4; ++i) {
      f32x4 acc = MFMA16(WF(i * 2), pa0, zf);
      acc = MFMA16(WF(i * 2 + 1), pa1, acc);
      c1[i] = acc + bec[i];
    }
    float sm = 0.f, sq = 0.f;
#pragma unroll
    for (int nt = 0; nt < 4; ++nt)
#pragma unroll
      for (int i = 0; i < 4; ++i) { sm += c1[nt][i]; sq += c1[nt][i] * c1[nt][i]; }
    sm += __shfl_xor(sm, 16); sq += __shfl_xor(sq, 16);
    sm += __shfl_xor(sm, 32); sq += __shfl_xor(sq, 32);
    float mean = sm * 0.015625f;
    float rstd = rsqrtf(sq * 0.015625f - mean * mean + 1e-5f);
#pragma unroll
    for (int nt = 0; nt < 4; ++nt) xh[nt] = (c1[nt] - mean) * rstd;
    short8 xa0 = packfrag(xh[0], xh[1]);
    short8 xa1 = packfrag(xh[2], xh[3]);
#pragma unroll
    for (int k = 0; k < 2; ++k) {
      f32x4 re = state[2 * k], im = state[2 * k + 1];
      state[2 * k]     = lbr[k] * re - lbi[k] * im + bu0c[2 * k];
      state[2 * k + 1] = lbr[k] * im + lbi[k] * re + bu0c[2 * k + 1];
    }
#pragma unroll
    for (int i = 0; i < 4; ++i) {
      state[i] = MFMA16(WF(8 + i * 2), xa0, state[i]);
      state[i] = MFMA16(WF(8 + i * 2 + 1), xa1, state[i]);
    }
#pragma unroll
    for (int q = 0; q < 4; ++q) vcur[q] = vnext[q];
  }

  // ---- head at t = 14 ----
  f32x4 g1c[4], b1c[4], Dc[4], g2c[4], b2c[4];
#pragma unroll
  for (int nt = 0; nt < 4; ++nt) {
    g1c[nt] = *(const f32x4*)(g1 + cb[nt]);
    b1c[nt] = *(const f32x4*)(be1 + cb[nt]);
    Dc[nt] = *(const f32x4*)(Dv + cb[nt]);
    g2c[nt] = *(const f32x4*)(g2 + cb[nt]);
    b2c[nt] = *(const f32x4*)(be2 + cb[nt]);
  }
  f32x4 fxl[4];
#pragma unroll
  for (int nt = 0; nt < 4; ++nt) fxl[nt] = xh[nt] * g1c[nt] + b1c[nt];

  short8 xsa0 = packfrag(state[0], state[1]);
  short8 xsa1 = packfrag(state[2], state[3]);
  f32x4 xbv[4];
#pragma unroll
  for (int i = 0; i < 4; ++i) {
    f32x4 acc = fxl[i] * Dc[i];
    acc = MFMA16(WF(16 + i * 2), xsa0, acc);
    acc = MFMA16(WF(16 + i * 2 + 1), xsa1, acc);
#pragma unroll
    for (int r = 0; r < 4; ++r) xbv[i][r] = geluf(acc[r]) + fxl[i][r];
  }
  float sm2 = 0.f, sq2 = 0.f;
#pragma unroll
  for (int nt = 0; nt < 4; ++nt)
#pragma unroll
    for (int i = 0; i < 4; ++i) { sm2 += xbv[nt][i]; sq2 += xbv[nt][i] * xbv[nt][i]; }
  sm2 += __shfl_xor(sm2, 16); sq2 += __shfl_xor(sq2, 16);
  sm2 += __shfl_xor(sm2, 32); sq2 += __shfl_xor(sq2, 32);
  float mean2 = sm2 * 0.015625f;
  float rstd2 = rsqrtf(sq2 * 0.015625f - mean2 * mean2 + 1e-5f);
  f32x4 fx2[4];
#pragma unroll
  for (int nt = 0; nt < 4; ++nt)
    fx2[nt] = (xbv[nt] - mean2) * rstd2 * g2c[nt] + b2c[nt];

  short8 fa0 = packfrag(fx2[0], fx2[1]);
  short8 fa1 = packfrag(fx2[2], fx2[3]);
  f32x4 e[8];
#pragma unroll
  for (int i = 0; i < 8; ++i) {
    f32x4 acc = MFMA16(WF(24 + i * 2), fa0, zf);
    e[i] = MFMA16(WF(24 + i * 2 + 1), fa1, acc);
  }
  f32x4 hv[4];
#pragma unroll
  for (int nt = 0; nt < 4; ++nt)
#pragma unroll
    for (int i = 0; i < 4; ++i) hv[nt][i] = e[nt][i] * geluf(e[nt + 4][i]);

  short8 ha0 = packfrag(hv[0], hv[1]);
  short8 ha1 = packfrag(hv[2], hv[3]);
  f32x4 xo[4];
#pragma unroll
  for (int i = 0; i < 4; ++i) {
    f32x4 acc = fx2[i];
    acc = MFMA16(WF(40 + i * 2), ha0, acc);
    xo[i] = MFMA16(WF(40 + i * 2 + 1), ha1, acc);
  }
  // store transposed: xlastT[d][seq], d-slot identity = kt*32+qd*8+j
#pragma unroll
  for (int kt = 0; kt < 2; ++kt)
#pragma unroll
    for (int j = 0; j < 8; ++j)
      xlastT[(kt * 32 + qd * 8 + j) * 38400 + sbase + s] = xo[2 * kt + (j >> 2)][j & 3];
#undef WF
}

// ---------------------------------------------------------------------------
// K2: LN3 + W_out(A-op) x z^T + b_out -> float4 pixel-shuffle stores.
// 256 thr = 4 waves x 16 seqs; block covers 64 seqs x 256 out-rows.
// ---------------------------------------------------------------------------
__global__ __launch_bounds__(256) void k2_head(
    const float* __restrict__ xlastT, const short* __restrict__ wout_img,
    const float* __restrict__ g3, const float* __restrict__ be3,
    const float* __restrict__ b_out, float* __restrict__ y) {
  __shared__ short wo[32 * 512];
  const int nqb = blockIdx.x & 3;
  const int mblk = blockIdx.x >> 2;
  {
    float4* dst = (float4*)wo;
    const float4* src = (const float4*)(wout_img + nqb * 32 * 512);
    for (int i = threadIdx.x; i < 2048; i += 256) dst[i] = src[i];
  }
  __syncthreads();
  const int wv = threadIdx.x >> 6, lane = threadIdx.x & 63;
  const int s = lane & 15, qd = lane >> 4;
  const int sbase = mblk * 64 + wv * 16;
  const int seq = sbase + s;
  const int nq0 = nqb * 256;

  float vals[2][8];
#pragma unroll
  for (int kt = 0; kt < 2; ++kt)
#pragma unroll
    for (int j = 0; j < 8; ++j)
      vals[kt][j] = xlastT[(kt * 32 + qd * 8 + j) * 38400 + seq];
  float sm = 0.f, sq = 0.f;
#pragma unroll
  for (int kt = 0; kt < 2; ++kt)
#pragma unroll
    for (int j = 0; j < 8; ++j) { sm += vals[kt][j]; sq += vals[kt][j] * vals[kt][j]; }
  sm += __shfl_xor(sm, 16); sq += __shfl_xor(sq, 16);
  sm += __shfl_xor(sm, 32); sq += __shfl_xor(sq, 32);
  float mean = sm * 0.015625f;
  float rstd = rsqrtf(sq * 0.015625f - mean * mean + 1e-5f);

  short8 zb[2];
#pragma unroll
  for (int kt = 0; kt < 2; ++kt) {
    f32x4 ga = *(const f32x4*)(g3 + kt * 32 + qd * 8);
    f32x4 gb = *(const f32x4*)(g3 + kt * 32 + qd * 8 + 4);
    f32x4 ba = *(const f32x4*)(be3 + kt * 32 + qd * 8);
    f32x4 bb = *(const f32x4*)(be3 + kt * 32 + qd * 8 + 4);
#pragma unroll
    for (int j = 0; j < 4; ++j) {
      zb[kt][j] = f2bf((vals[kt][j] - mean) * rstd * ga[j] + ba[j]);
      zb[kt][j + 4] = f2bf((vals[kt][j + 4] - mean) * rstd * gb[j] + bb[j]);
    }
  }
  const int bi2 = seq / 4800, prr = seq % 4800;
  const int phh = prr / 80, pww = prr % 80;
  const int obase = (bi2 * 16 * 480 + phh * 8) * 640 + pww * 8;

#pragma unroll
  for (int nt = 0; nt < 16; ++nt) {
    int o0 = nq0 + nt * 16 + qd * 4;
    f32x4 acc = *(const f32x4*)(b_out + o0);
    acc = MFMA16(*(const short8*)&wo[(nt * 2 + 0) * 512 + lane * 8], zb[0], acc);
    acc = MFMA16(*(const short8*)&wo[(nt * 2 + 1) * 512 + lane * 8], zb[1], acc);
    int c = o0 >> 6, pi = (o0 >> 3) & 7, pj = o0 & 7;
    *(f32x4*)&y[obase + c * 307200 + pi * 640 + pj] = acc;
  }
}

// ---------------------------------------------------------------------------
extern "C" void kernel_launch(void* const* d_in, const int* in_sizes, int n_in,
                              void* d_out, int out_size, void* d_ws, size_t ws_size,
                              hipStream_t stream) {
  const float* x       = (const float*)d_in[0];
  const float* W_embed = (const float*)d_in[1];
  const float* b_embed = (const float*)d_in[2];
  const float* g1      = (const float*)d_in[3];
  const float* beta1   = (const float*)d_in[4];
  const float* Lre     = (const float*)d_in[5];
  const float* Lim     = (const float*)d_in[6];
  const float* Bre     = (const float*)d_in[7];
  const float* Bim     = (const float*)d_in[8];
  const float* Cre     = (const float*)d_in[9];
  const float* Cim     = (const float*)d_in[10];
  const float* Dv      = (const float*)d_in[11];
  const float* lstep   = (const float*)d_in[12];
  const float* g2      = (const float*)d_in[13];
  const float* beta2   = (const float*)d_in[14];
  const float* W_enc   = (const float*)d_in[15];
  const float* W_dec   = (const float*)d_in[16];
  const float* g3      = (const float*)d_in[17];
  const float* beta3   = (const float*)d_in[18];
  const float* W_out   = (const float*)d_in[19];
  const float* b_out   = (const float*)d_in[20];
  float* y = (float*)d_out;

  short* wimg = (short*)d_ws;                          // 176 KB frag images
  float* bu0 = (float*)((char*)d_ws + 176 * 1024);     // 256 B
  float* xlastT = (float*)((char*)d_ws + 180 * 1024);  // 64 x 38400 f32

  k0_prep<<<dim3(45), dim3(256), 0, stream>>>(W_embed, g1, beta1, Lre, Lim,
                                              Bre, Bim, Cre, Cim, lstep,
                                              W_enc, W_dec, W_out, wimg, bu0);
  k1_fused<<<dim3(600), dim3(256), 0, stream>>>(x, wimg, bu0, Lre, Lim, lstep,
                                                g1, beta1, b_embed, Dv, g2,
                                                beta2, xlastT);
  k2_head<<<dim3(2400), dim3(256), 0, stream>>>(xlastT, wimg + 48 * 512, g3,
                                                beta3, b_out, y);
}